// Round 2
// 720.137 us; speedup vs baseline: 1.0800x; 1.0800x over previous
//
#include <hip/hip_runtime.h>
#include <stdint.h>

// ThorMoE: per-expert 2-layer MLP.
// E=16, T=512, H=1024, I=4096. fp32 in/out, f16 MFMA compute internally
// (threshold is 2% of max|ref| -> f16+fp32-accum error ~0.2%, safe).
// Kernel 1: h[e,t,i] = x[e,t,:] @ W1[e,:,i] + b1[e,i]   (M=512,N=4096,K=1024), h in ws as f16
// Kernel 2: y[e,t,h] = h[e,t,:] @ W2[e,:,h] + b2[e,h]   (M=512,N=1024,K=4096), y fp32 to d_out
// 128x128 tile, BK=32, 256 threads = 4 waves (2x2), 4x4 16x16x32 MFMA frags/wave.
// B (weights) are N-contiguous; staged transposed into LDS [n][k].
//
// R1 (re-run R2: prior bench attempt died to container infra, no signal):
//   all LDS staging writes are conflict-free ds_write_b128.
//   Old B-transpose staging did 8x ds_write_b32 per thread at 80B row stride
//   -> 16-way bank conflict (7.55e7 conflict cycles = ~56% of kernel cycles).
//   New: thread gathers 16 k's for one n (coalesced dword loads along n),
//   packs with cvt_pkrtz, writes two b128. Lane->row bank-quad stride
//   20 mod 32 covers all 32 banks per 8 lanes -> conflict-free.

#define E_ 16
#define T_ 512
#define H_ 1024
#define I_ 4096

typedef _Float16 f16x8 __attribute__((ext_vector_type(8)));
typedef __fp16   h2    __attribute__((ext_vector_type(2)));  // cvt_pkrtz result type
typedef float    f32x4 __attribute__((ext_vector_type(4)));

#define LDK 40  // LDS row stride in f16 elems: 32 + 8 pad (16B-aligned rows, bank-quad stride 20 mod 32)

template <bool A_IS_F16, bool OUT_IS_F16>
__global__ __launch_bounds__(256, 2) void moe_gemm(const void* __restrict__ Aall,
                                                   const float* __restrict__ Ball,
                                                   const float* __restrict__ biasAll,
                                                   void* __restrict__ Call,
                                                   int M, int N, int K) {
    __shared__ _Float16 sA[128 * LDK];
    __shared__ _Float16 sB[128 * LDK];

    const int e   = blockIdx.z;
    const int m0  = blockIdx.y * 128;
    const int n0  = blockIdx.x * 128;
    const int tid = threadIdx.x;
    const int lane = tid & 63;
    const int wave = tid >> 6;
    const int wm = (wave >> 1) * 64;   // wave row offset in tile
    const int wn = (wave & 1) * 64;    // wave col offset in tile
    const int lrow = lane & 15;        // m (or n) within 16x16 frag
    const int lk8  = (lane >> 4) * 8;  // k offset within frag

    const float* B_e    = Ball + (size_t)e * K * N;
    const float* bias_e = biasAll + (size_t)e * N;
    const float*     A_f32 = (const float*)Aall + (size_t)e * M * K;
    const _Float16*  A_f16 = (const _Float16*)Aall + (size_t)e * M * K;

    // --- staging index precompute ---
    // B: thread owns one n-column (bn) and 16 consecutive k's starting at bkh.
    //    tid 0..127 -> bn 0..127, kh 0; tid 128..255 -> bn 0..127, kh 16.
    const int bn  = ((tid >> 6) & 1) * 64 + (tid & 63);  // 0..127
    const int bkh = (tid >> 7) * 16;                     // 0 or 16
    // A fp32: thread owns rows {ar, ar+16} x 8 k's at ak.
    const int ar = (tid >> 6) * 32 + ((tid & 63) >> 2);  // wave*32 + (L>>2): 0..15
    const int ak = (tid & 3) * 8;                        // 0,8,16,24

    f32x4 acc[4][4];
    const f32x4 zero = {0.f, 0.f, 0.f, 0.f};
#pragma unroll
    for (int i = 0; i < 4; ++i)
#pragma unroll
        for (int j = 0; j < 4; ++j) acc[i][j] = zero;

    for (int k0 = 0; k0 < K; k0 += 32) {
        // ---- stage A tile: [128 rows m][32 k], k-contiguous in LDS ----
        if (A_IS_F16) {
            const int r  = tid >> 2;          // 0..63
            const int c8 = (tid & 3) * 8;     // 0,8,16,24
#pragma unroll
            for (int p = 0; p < 2; ++p) {
                const int row = r + p * 64;
                f16x8 v = *(const f16x8*)(A_f16 + (size_t)(m0 + row) * K + k0 + c8);
                *(f16x8*)&sA[row * LDK + c8] = v;
            }
        } else {
#pragma unroll
            for (int p = 0; p < 2; ++p) {
                const int row = ar + p * 16;
                const float* asrc = A_f32 + (size_t)(m0 + row) * K + k0 + ak;
                f32x4 va = *(const f32x4*)asrc;
                f32x4 vb = *(const f32x4*)(asrc + 4);
                f16x8 w;
                ((h2*)&w)[0] = __builtin_amdgcn_cvt_pkrtz(va.x, va.y);
                ((h2*)&w)[1] = __builtin_amdgcn_cvt_pkrtz(va.z, va.w);
                ((h2*)&w)[2] = __builtin_amdgcn_cvt_pkrtz(vb.x, vb.y);
                ((h2*)&w)[3] = __builtin_amdgcn_cvt_pkrtz(vb.z, vb.w);
                *(f16x8*)&sA[row * LDK + ak] = w;
            }
        }
        // ---- stage B tile with transpose: global [k][n] -> LDS [n][k] ----
        {
            const float* bsrc = B_e + (size_t)(k0 + bkh) * N + n0 + bn;
            float bv[16];
#pragma unroll
            for (int kk = 0; kk < 16; ++kk)
                bv[kk] = bsrc[(size_t)kk * N];   // coalesced: lanes = consecutive n
            f16x8 w0, w1;
#pragma unroll
            for (int j = 0; j < 4; ++j) {
                ((h2*)&w0)[j] = __builtin_amdgcn_cvt_pkrtz(bv[2 * j],     bv[2 * j + 1]);
                ((h2*)&w1)[j] = __builtin_amdgcn_cvt_pkrtz(bv[8 + 2 * j], bv[8 + 2 * j + 1]);
            }
            *(f16x8*)&sB[bn * LDK + bkh]     = w0;
            *(f16x8*)&sB[bn * LDK + bkh + 8] = w1;
        }
        __syncthreads();

        // ---- fragments + MFMA ----
        f16x8 af[4], bf[4];
#pragma unroll
        for (int mi = 0; mi < 4; ++mi)
            af[mi] = *(const f16x8*)&sA[(wm + mi * 16 + lrow) * LDK + lk8];
#pragma unroll
        for (int ni = 0; ni < 4; ++ni)
            bf[ni] = *(const f16x8*)&sB[(wn + ni * 16 + lrow) * LDK + lk8];
#pragma unroll
        for (int mi = 0; mi < 4; ++mi)
#pragma unroll
            for (int ni = 0; ni < 4; ++ni)
                acc[mi][ni] = __builtin_amdgcn_mfma_f32_16x16x32_f16(af[mi], bf[ni], acc[mi][ni], 0, 0, 0);
        __syncthreads();
    }

    // ---- epilogue: C/D layout col=lane&15, row=(lane>>4)*4+reg (verified m89/m91) ----
    const int row_base = (lane >> 4) * 4;
#pragma unroll
    for (int ni = 0; ni < 4; ++ni) {
        const int n = n0 + wn + ni * 16 + lrow;
        const float bv = bias_e[n];
#pragma unroll
        for (int mi = 0; mi < 4; ++mi) {
            const int mbase = m0 + wm + mi * 16 + row_base;
#pragma unroll
            for (int r = 0; r < 4; ++r) {
                const float val = acc[mi][ni][r] + bv;
                const size_t idx = (size_t)e * M * N + (size_t)(mbase + r) * N + n;
                if (OUT_IS_F16)
                    ((_Float16*)Call)[idx] = (_Float16)val;
                else
                    ((float*)Call)[idx] = val;
            }
        }
    }
}

extern "C" void kernel_launch(void* const* d_in, const int* in_sizes, int n_in,
                              void* d_out, int out_size, void* d_ws, size_t ws_size,
                              hipStream_t stream) {
    (void)in_sizes; (void)n_in; (void)out_size; (void)ws_size;
    const float* x  = (const float*)d_in[0];  // (E,T,H)
    const float* W1 = (const float*)d_in[1];  // (E,H,I)
    const float* b1 = (const float*)d_in[2];  // (E,I)
    const float* W2 = (const float*)d_in[3];  // (E,I,H)
    const float* b2 = (const float*)d_in[4];  // (E,H)
    float* out = (float*)d_out;               // (E*T, H) fp32
    _Float16* hbuf = (_Float16*)d_ws;         // (E,T,I) f16 intermediate, 67.1 MB

    dim3 blk(256, 1, 1);
    dim3 g1(I_ / 128, T_ / 128, E_);  // 32 x 4 x 16 = 2048 blocks
    moe_gemm<false, true><<<g1, blk, 0, stream>>>((const void*)x, W1, b1, (void*)hbuf, T_, I_, H_);
    dim3 g2(H_ / 128, T_ / 128, E_);  // 8 x 4 x 16 = 512 blocks
    moe_gemm<true, false><<<g2, blk, 0, stream>>>((const void*)hbuf, W2, b2, (void*)out, T_, H_, I_);
}

// Round 3
// 705.904 us; speedup vs baseline: 1.1018x; 1.0202x over previous
//
#include <hip/hip_runtime.h>
#include <stdint.h>

// ThorMoE: per-expert 2-layer MLP.
// E=16, T=512, H=1024, I=4096. fp32 in/out, f16 MFMA compute internally
// (threshold is 2% of max|ref| -> f16+fp32-accum error ~0.2%, safe).
// Kernel 1: h[e,t,i] = x[e,t,:] @ W1[e,:,i] + b1[e,i]   (M=512,N=4096,K=1024), h in ws as f16
// Kernel 2: y[e,t,h] = h[e,t,:] @ W2[e,:,h] + b2[e,h]   (M=512,N=1024,K=4096), y fp32 to d_out
// 128x128 tile, BK=32, 256 threads = 4 waves (2x2), 4x4 16x16x32 MFMA frags/wave.
// B (weights) are N-contiguous; staged transposed into LDS [n][k].
//
// R1: conflict-free ds_write_b128 staging (bank conflicts 7.55e7 -> 1.26e7,
//     220 -> 183 us/dispatch).
// R3: T14 register-prefetch software pipeline. Old loop exposed full global
//     load latency on the critical path every K-step (MfmaUtil 15%, VALUBusy
//     12%, occupancy 21-38% -- latency-bound, 3x above memory roofline).
//     Now: tile k+1's global loads issue right after tile k's regs are
//     consumed by ds_write, and stay in flight across the MFMA phase.
//     Single LDS buffer (20 KB), +32 VGPRs for the in-flight tile.

#define E_ 16
#define T_ 512
#define H_ 1024
#define I_ 4096

typedef _Float16 f16x8 __attribute__((ext_vector_type(8)));
typedef __fp16   h2    __attribute__((ext_vector_type(2)));  // cvt_pkrtz result type
typedef float    f32x4 __attribute__((ext_vector_type(4)));

#define LDK 40  // LDS row stride in f16 elems: 32 + 8 pad (16B-aligned rows, bank-quad stride 20 mod 32)

template <bool A_IS_F16, bool OUT_IS_F16>
__global__ __launch_bounds__(256, 2) void moe_gemm(const void* __restrict__ Aall,
                                                   const float* __restrict__ Ball,
                                                   const float* __restrict__ biasAll,
                                                   void* __restrict__ Call,
                                                   int M, int N, int K) {
    __shared__ _Float16 sA[128 * LDK];
    __shared__ _Float16 sB[128 * LDK];

    const int e   = blockIdx.z;
    const int m0  = blockIdx.y * 128;
    const int n0  = blockIdx.x * 128;
    const int tid = threadIdx.x;
    const int lane = tid & 63;
    const int wave = tid >> 6;
    const int wm = (wave >> 1) * 64;   // wave row offset in tile
    const int wn = (wave & 1) * 64;    // wave col offset in tile
    const int lrow = lane & 15;        // m (or n) within 16x16 frag
    const int lk8  = (lane >> 4) * 8;  // k offset within frag

    const float* B_e    = Ball + (size_t)e * K * N;
    const float* bias_e = biasAll + (size_t)e * N;
    const float*     A_f32 = (const float*)Aall + (size_t)e * M * K;
    const _Float16*  A_f16 = (const _Float16*)Aall + (size_t)e * M * K;

    // --- staging index precompute ---
    // B: thread owns one n-column (bn) and 16 consecutive k's starting at bkh.
    const int bn  = ((tid >> 6) & 1) * 64 + (tid & 63);  // 0..127
    const int bkh = (tid >> 7) * 16;                     // 0 or 16
    // A fp32: thread owns rows {ar, ar+16} x 8 k's at ak.
    const int ar = (tid >> 6) * 32 + ((tid & 63) >> 2);  // 0..15 per half
    const int ak = (tid & 3) * 8;                        // 0,8,16,24
    // A f16: thread owns rows {r, r+64} x 8 k's at c8.
    const int r  = tid >> 2;                             // 0..63
    const int c8 = (tid & 3) * 8;                        // 0,8,16,24

    // --- register staging buffers (the in-flight tile) ---
    float bv[16];
    f32x4 a32[4];   // fp32 A path: rows {ar, ar+16} x 2 f32x4 each
    f16x8 a16[2];   // f16  A path: rows {r, r+64}

    auto load_tile = [&](int k0) {
        const float* bsrc = B_e + (size_t)(k0 + bkh) * N + n0 + bn;
#pragma unroll
        for (int kk = 0; kk < 16; ++kk)
            bv[kk] = bsrc[(size_t)kk * N];   // coalesced: lanes = consecutive n
        if (A_IS_F16) {
            a16[0] = *(const f16x8*)(A_f16 + (size_t)(m0 + r) * K + k0 + c8);
            a16[1] = *(const f16x8*)(A_f16 + (size_t)(m0 + r + 64) * K + k0 + c8);
        } else {
            const float* a0 = A_f32 + (size_t)(m0 + ar) * K + k0 + ak;
            a32[0] = *(const f32x4*)a0;
            a32[1] = *(const f32x4*)(a0 + 4);
            const float* a1 = A_f32 + (size_t)(m0 + ar + 16) * K + k0 + ak;
            a32[2] = *(const f32x4*)a1;
            a32[3] = *(const f32x4*)(a1 + 4);
        }
    };

    auto store_tile = [&]() {
        // B: pack 16 k's for column bn, two conflict-free b128 writes.
        f16x8 w0, w1;
#pragma unroll
        for (int j = 0; j < 4; ++j) {
            ((h2*)&w0)[j] = __builtin_amdgcn_cvt_pkrtz(bv[2 * j],     bv[2 * j + 1]);
            ((h2*)&w1)[j] = __builtin_amdgcn_cvt_pkrtz(bv[8 + 2 * j], bv[8 + 2 * j + 1]);
        }
        *(f16x8*)&sB[bn * LDK + bkh]     = w0;
        *(f16x8*)&sB[bn * LDK + bkh + 8] = w1;
        // A
        if (A_IS_F16) {
            *(f16x8*)&sA[r * LDK + c8]        = a16[0];
            *(f16x8*)&sA[(r + 64) * LDK + c8] = a16[1];
        } else {
#pragma unroll
            for (int p = 0; p < 2; ++p) {
                f16x8 w;
                ((h2*)&w)[0] = __builtin_amdgcn_cvt_pkrtz(a32[2 * p].x, a32[2 * p].y);
                ((h2*)&w)[1] = __builtin_amdgcn_cvt_pkrtz(a32[2 * p].z, a32[2 * p].w);
                ((h2*)&w)[2] = __builtin_amdgcn_cvt_pkrtz(a32[2 * p + 1].x, a32[2 * p + 1].y);
                ((h2*)&w)[3] = __builtin_amdgcn_cvt_pkrtz(a32[2 * p + 1].z, a32[2 * p + 1].w);
                *(f16x8*)&sA[(ar + p * 16) * LDK + ak] = w;
            }
        }
    };

    f32x4 acc[4][4];
    const f32x4 zero = {0.f, 0.f, 0.f, 0.f};
#pragma unroll
    for (int i = 0; i < 4; ++i)
#pragma unroll
        for (int j = 0; j < 4; ++j) acc[i][j] = zero;

    load_tile(0);  // prologue

    for (int k0 = 0; k0 < K; k0 += 32) {
        __syncthreads();          // previous iteration's LDS reads complete
        store_tile();             // regs -> LDS (implicit vmcnt wait on reg deps)
        if (k0 + 32 < K)
            load_tile(k0 + 32);   // issue next tile; in flight across MFMA phase
        __syncthreads();          // LDS writes visible

        // ---- fragments + MFMA ----
        f16x8 af[4], bf[4];
#pragma unroll
        for (int mi = 0; mi < 4; ++mi)
            af[mi] = *(const f16x8*)&sA[(wm + mi * 16 + lrow) * LDK + lk8];
#pragma unroll
        for (int ni = 0; ni < 4; ++ni)
            bf[ni] = *(const f16x8*)&sB[(wn + ni * 16 + lrow) * LDK + lk8];
#pragma unroll
        for (int mi = 0; mi < 4; ++mi)
#pragma unroll
            for (int ni = 0; ni < 4; ++ni)
                acc[mi][ni] = __builtin_amdgcn_mfma_f32_16x16x32_f16(af[mi], bf[ni], acc[mi][ni], 0, 0, 0);
    }

    // ---- epilogue: C/D layout col=lane&15, row=(lane>>4)*4+reg (verified m89/m91) ----
    const int row_base = (lane >> 4) * 4;
#pragma unroll
    for (int ni = 0; ni < 4; ++ni) {
        const int n = n0 + wn + ni * 16 + lrow;
        const float bv2 = bias_e[n];
#pragma unroll
        for (int mi = 0; mi < 4; ++mi) {
            const int mbase = m0 + wm + mi * 16 + row_base;
#pragma unroll
            for (int rr = 0; rr < 4; ++rr) {
                const float val = acc[mi][ni][rr] + bv2;
                const size_t idx = (size_t)e * M * N + (size_t)(mbase + rr) * N + n;
                if (OUT_IS_F16)
                    ((_Float16*)Call)[idx] = (_Float16)val;
                else
                    ((float*)Call)[idx] = val;
            }
        }
    }
}

extern "C" void kernel_launch(void* const* d_in, const int* in_sizes, int n_in,
                              void* d_out, int out_size, void* d_ws, size_t ws_size,
                              hipStream_t stream) {
    (void)in_sizes; (void)n_in; (void)out_size; (void)ws_size;
    const float* x  = (const float*)d_in[0];  // (E,T,H)
    const float* W1 = (const float*)d_in[1];  // (E,H,I)
    const float* b1 = (const float*)d_in[2];  // (E,I)
    const float* W2 = (const float*)d_in[3];  // (E,I,H)
    const float* b2 = (const float*)d_in[4];  // (E,H)
    float* out = (float*)d_out;               // (E*T, H) fp32
    _Float16* hbuf = (_Float16*)d_ws;         // (E,T,I) f16 intermediate, 67.1 MB

    dim3 blk(256, 1, 1);
    dim3 g1(I_ / 128, T_ / 128, E_);  // 32 x 4 x 16 = 2048 blocks
    moe_gemm<false, true><<<g1, blk, 0, stream>>>((const void*)x, W1, b1, (void*)hbuf, T_, I_, H_);
    dim3 g2(H_ / 128, T_ / 128, E_);  // 8 x 4 x 16 = 512 blocks
    moe_gemm<true, false><<<g2, blk, 0, stream>>>((const void*)hbuf, W2, b2, (void*)out, T_, H_, I_);
}

// Round 4
// 697.414 us; speedup vs baseline: 1.1152x; 1.0122x over previous
//
#include <hip/hip_runtime.h>
#include <stdint.h>

// ThorMoE: per-expert 2-layer MLP.
// E=16, T=512, H=1024, I=4096. fp32 in/out, f16 MFMA compute internally.
// Kernel 1: h[e,t,i] = x @ W1 + b1   (M=512,N=4096,K=1024), h in ws as f16
// Kernel 2: y[e,t,h] = h @ W2 + b2   (M=512,N=1024,K=4096), y fp32 to d_out
// 128x128 tile, BK=32, 256 threads = 4 waves (2x2), 4x4 16x16x32 MFMA frags/wave.
//
// R1: conflict-free ds_write_b128 staging (conflicts 7.55e7 -> 1.26e7, 220->183us).
// R3: reg-prefetch (T14): +3% only (183->178us) -- matches m249: the 2-phase
//     barrier structure is the wall, not load latency.
// R4: double-buffered LDS, ONE barrier per K-step, staging ds_writes issued
//     between MFMA halves so they overlap compute on the other buffer.
//     Removes one barrier drain per step and takes ds_write off the
//     critical path. LDS 40 KB -> still 4 blocks/CU (>= measured 2.4).

#define E_ 16
#define T_ 512
#define H_ 1024
#define I_ 4096

typedef _Float16 f16x8 __attribute__((ext_vector_type(8)));
typedef __fp16   h2    __attribute__((ext_vector_type(2)));  // cvt_pkrtz result type
typedef float    f32x4 __attribute__((ext_vector_type(4)));

#define LDK 40  // LDS row stride in f16 elems: 32 + 8 pad (16B-aligned rows, bank-quad stride 20 mod 32)

template <bool A_IS_F16, bool OUT_IS_F16>
__global__ __launch_bounds__(256, 2) void moe_gemm(const void* __restrict__ Aall,
                                                   const float* __restrict__ Ball,
                                                   const float* __restrict__ biasAll,
                                                   void* __restrict__ Call,
                                                   int M, int N, int K) {
    __shared__ _Float16 sA[2][128 * LDK];
    __shared__ _Float16 sB[2][128 * LDK];

    const int e   = blockIdx.z;
    const int m0  = blockIdx.y * 128;
    const int n0  = blockIdx.x * 128;
    const int tid = threadIdx.x;
    const int lane = tid & 63;
    const int wave = tid >> 6;
    const int wm = (wave >> 1) * 64;   // wave row offset in tile
    const int wn = (wave & 1) * 64;    // wave col offset in tile
    const int lrow = lane & 15;        // m (or n) within 16x16 frag
    const int lk8  = (lane >> 4) * 8;  // k offset within frag

    const float* B_e    = Ball + (size_t)e * K * N;
    const float* bias_e = biasAll + (size_t)e * N;
    const float*     A_f32 = (const float*)Aall + (size_t)e * M * K;
    const _Float16*  A_f16 = (const _Float16*)Aall + (size_t)e * M * K;

    // --- staging index precompute ---
    // B: thread owns one n-column (bn) and 16 consecutive k's starting at bkh.
    const int bn  = ((tid >> 6) & 1) * 64 + (tid & 63);  // 0..127
    const int bkh = (tid >> 7) * 16;                     // 0 or 16
    // A fp32: thread owns rows {ar, ar+16} x 8 k's at ak.
    const int ar = (tid >> 6) * 32 + ((tid & 63) >> 2);  // 0..15 per half
    const int ak = (tid & 3) * 8;                        // 0,8,16,24
    // A f16: thread owns rows {r, r+64} x 8 k's at c8.
    const int r  = tid >> 2;                             // 0..63
    const int c8 = (tid & 3) * 8;                        // 0,8,16,24

    // --- register staging buffers (the in-flight tile) ---
    float bv[16];
    f32x4 a32[4];   // fp32 A path: rows {ar, ar+16} x 2 f32x4 each
    f16x8 a16[2];   // f16  A path: rows {r, r+64}

    auto load_tile = [&](int k0) {
        const float* bsrc = B_e + (size_t)(k0 + bkh) * N + n0 + bn;
#pragma unroll
        for (int kk = 0; kk < 16; ++kk)
            bv[kk] = bsrc[(size_t)kk * N];   // coalesced: lanes = consecutive n
        if (A_IS_F16) {
            a16[0] = *(const f16x8*)(A_f16 + (size_t)(m0 + r) * K + k0 + c8);
            a16[1] = *(const f16x8*)(A_f16 + (size_t)(m0 + r + 64) * K + k0 + c8);
        } else {
            const float* a0 = A_f32 + (size_t)(m0 + ar) * K + k0 + ak;
            a32[0] = *(const f32x4*)a0;
            a32[1] = *(const f32x4*)(a0 + 4);
            const float* a1 = A_f32 + (size_t)(m0 + ar + 16) * K + k0 + ak;
            a32[2] = *(const f32x4*)a1;
            a32[3] = *(const f32x4*)(a1 + 4);
        }
    };

    auto store_tile = [&](_Float16* dA, _Float16* dB) {
        // B: pack 16 k's for column bn, two conflict-free b128 writes.
        f16x8 w0, w1;
#pragma unroll
        for (int j = 0; j < 4; ++j) {
            ((h2*)&w0)[j] = __builtin_amdgcn_cvt_pkrtz(bv[2 * j],     bv[2 * j + 1]);
            ((h2*)&w1)[j] = __builtin_amdgcn_cvt_pkrtz(bv[8 + 2 * j], bv[8 + 2 * j + 1]);
        }
        *(f16x8*)&dB[bn * LDK + bkh]     = w0;
        *(f16x8*)&dB[bn * LDK + bkh + 8] = w1;
        // A
        if (A_IS_F16) {
            *(f16x8*)&dA[r * LDK + c8]        = a16[0];
            *(f16x8*)&dA[(r + 64) * LDK + c8] = a16[1];
        } else {
#pragma unroll
            for (int p = 0; p < 2; ++p) {
                f16x8 w;
                ((h2*)&w)[0] = __builtin_amdgcn_cvt_pkrtz(a32[2 * p].x, a32[2 * p].y);
                ((h2*)&w)[1] = __builtin_amdgcn_cvt_pkrtz(a32[2 * p].z, a32[2 * p].w);
                ((h2*)&w)[2] = __builtin_amdgcn_cvt_pkrtz(a32[2 * p + 1].x, a32[2 * p + 1].y);
                ((h2*)&w)[3] = __builtin_amdgcn_cvt_pkrtz(a32[2 * p + 1].z, a32[2 * p + 1].w);
                *(f16x8*)&dA[(ar + p * 16) * LDK + ak] = w;
            }
        }
    };

    f32x4 acc[4][4];
    const f32x4 zero = {0.f, 0.f, 0.f, 0.f};
#pragma unroll
    for (int i = 0; i < 4; ++i)
#pragma unroll
        for (int j = 0; j < 4; ++j) acc[i][j] = zero;

    const int nt = K / 32;

    // ---- prologue: tile 0 -> buf0; tile 1 loads in flight ----
    load_tile(0);
    store_tile(sA[0], sB[0]);
    load_tile(32);
    __syncthreads();

    for (int t = 0; t < nt; ++t) {
        const int cur = t & 1;
        const _Float16* rA = sA[cur];
        const _Float16* rB = sB[cur];

        // ---- fragment reads from current buffer ----
        f16x8 af[4], bf[4];
#pragma unroll
        for (int mi = 0; mi < 4; ++mi)
            af[mi] = *(const f16x8*)&rA[(wm + mi * 16 + lrow) * LDK + lk8];
#pragma unroll
        for (int ni = 0; ni < 4; ++ni)
            bf[ni] = *(const f16x8*)&rB[(wn + ni * 16 + lrow) * LDK + lk8];

        // ---- first half of MFMAs ----
#pragma unroll
        for (int mi = 0; mi < 2; ++mi)
#pragma unroll
            for (int ni = 0; ni < 4; ++ni)
                acc[mi][ni] = __builtin_amdgcn_mfma_f32_16x16x32_f16(af[mi], bf[ni], acc[mi][ni], 0, 0, 0);

        // ---- stage tile t+1 into the other buffer (overlaps MFMA pipe) ----
        if (t + 1 < nt) {
            store_tile(sA[cur ^ 1], sB[cur ^ 1]);   // vmcnt wait on tile t+1 regs
            if (t + 2 < nt)
                load_tile((t + 2) * 32);            // issue tile t+2; in flight 1 full iter
        }

        // ---- second half of MFMAs ----
#pragma unroll
        for (int mi = 2; mi < 4; ++mi)
#pragma unroll
            for (int ni = 0; ni < 4; ++ni)
                acc[mi][ni] = __builtin_amdgcn_mfma_f32_16x16x32_f16(af[mi], bf[ni], acc[mi][ni], 0, 0, 0);

        // one barrier per K-step: separates this iter's reads of buf[cur] and
        // writes of buf[cur^1] from next iter's writes/reads.
        __syncthreads();
    }

    // ---- epilogue: C/D layout col=lane&15, row=(lane>>4)*4+reg (verified m89/m91) ----
    const int row_base = (lane >> 4) * 4;
#pragma unroll
    for (int ni = 0; ni < 4; ++ni) {
        const int n = n0 + wn + ni * 16 + lrow;
        const float bv2 = bias_e[n];
#pragma unroll
        for (int mi = 0; mi < 4; ++mi) {
            const int mbase = m0 + wm + mi * 16 + row_base;
#pragma unroll
            for (int rr = 0; rr < 4; ++rr) {
                const float val = acc[mi][ni][rr] + bv2;
                const size_t idx = (size_t)e * M * N + (size_t)(mbase + rr) * N + n;
                if (OUT_IS_F16)
                    ((_Float16*)Call)[idx] = (_Float16)val;
                else
                    ((float*)Call)[idx] = val;
            }
        }
    }
}

extern "C" void kernel_launch(void* const* d_in, const int* in_sizes, int n_in,
                              void* d_out, int out_size, void* d_ws, size_t ws_size,
                              hipStream_t stream) {
    (void)in_sizes; (void)n_in; (void)out_size; (void)ws_size;
    const float* x  = (const float*)d_in[0];  // (E,T,H)
    const float* W1 = (const float*)d_in[1];  // (E,H,I)
    const float* b1 = (const float*)d_in[2];  // (E,I)
    const float* W2 = (const float*)d_in[3];  // (E,I,H)
    const float* b2 = (const float*)d_in[4];  // (E,H)
    float* out = (float*)d_out;               // (E*T, H) fp32
    _Float16* hbuf = (_Float16*)d_ws;         // (E,T,I) f16 intermediate, 67.1 MB

    dim3 blk(256, 1, 1);
    dim3 g1(I_ / 128, T_ / 128, E_);  // 32 x 4 x 16 = 2048 blocks
    moe_gemm<false, true><<<g1, blk, 0, stream>>>((const void*)x, W1, b1, (void*)hbuf, T_, I_, H_);
    dim3 g2(H_ / 128, T_ / 128, E_);  // 8 x 4 x 16 = 512 blocks
    moe_gemm<true, false><<<g2, blk, 0, stream>>>((const void*)hbuf, W2, b2, (void*)out, T_, H_, I_);
}

// Round 5
// 695.778 us; speedup vs baseline: 1.1178x; 1.0024x over previous
//
#include <hip/hip_runtime.h>
#include <stdint.h>

// ThorMoE: per-expert 2-layer MLP.
// E=16, T=512, H=1024, I=4096. fp32 in/out, f16 MFMA compute internally.
// Kernel 1: h[e,t,i] = x @ W1 + b1   (M=512,N=4096,K=1024), h in ws as f16
// Kernel 2: y[e,t,h] = h @ W2 + b2   (M=512,N=1024,K=4096), y fp32 to d_out
// 128x128 tile, BK=32, 256 threads = 4 waves (2x2), 4x4 16x16x32 MFMA frags/wave.
//
// R1: conflict-free ds_write_b128 staging (conflicts 7.55e7 -> 1.26e7, 220->183us).
// R3: reg-prefetch (T14): +3% (183->178). R4: dbuf + 1 barrier/step: +0%.
// R5: THE FIX for why R3/R4 were null: __syncthreads() emits
//     s_waitcnt vmcnt(0) before s_barrier, draining the tile-t+2 prefetch
//     loads every iteration -- the pipeline never stayed in flight (m97
//     ceiling mechanism; m218: counted-vmcnt vs drain0 = +38..73%).
//     Replace with raw s_barrier + s_waitcnt lgkmcnt(0) ONLY: prefetch
//     targets registers, so no vmcnt drain is semantically needed; ds_write
//     visibility only needs lgkm. vmcnt never hits 0 in the main loop.

#define E_ 16
#define T_ 512
#define H_ 1024
#define I_ 4096

typedef _Float16 f16x8 __attribute__((ext_vector_type(8)));
typedef __fp16   h2    __attribute__((ext_vector_type(2)));  // cvt_pkrtz result type
typedef float    f32x4 __attribute__((ext_vector_type(4)));

#define LDK 40  // LDS row stride in f16 elems: 32 + 8 pad (16B-aligned rows, bank-quad stride 20 mod 32)

// Raw barrier: drain own LDS ops (write visibility / read completion), but
// leave global loads in flight across the barrier.
__device__ __forceinline__ void lds_barrier() {
    __builtin_amdgcn_sched_barrier(0);
    asm volatile("s_waitcnt lgkmcnt(0)" ::: "memory");
    __builtin_amdgcn_sched_barrier(0);
    __builtin_amdgcn_s_barrier();
    __builtin_amdgcn_sched_barrier(0);
}

template <bool A_IS_F16, bool OUT_IS_F16>
__global__ __launch_bounds__(256, 2) void moe_gemm(const void* __restrict__ Aall,
                                                   const float* __restrict__ Ball,
                                                   const float* __restrict__ biasAll,
                                                   void* __restrict__ Call,
                                                   int M, int N, int K) {
    __shared__ _Float16 sA[2][128 * LDK];
    __shared__ _Float16 sB[2][128 * LDK];

    const int e   = blockIdx.z;
    const int m0  = blockIdx.y * 128;
    const int n0  = blockIdx.x * 128;
    const int tid = threadIdx.x;
    const int lane = tid & 63;
    const int wave = tid >> 6;
    const int wm = (wave >> 1) * 64;   // wave row offset in tile
    const int wn = (wave & 1) * 64;    // wave col offset in tile
    const int lrow = lane & 15;        // m (or n) within 16x16 frag
    const int lk8  = (lane >> 4) * 8;  // k offset within frag

    const float* B_e    = Ball + (size_t)e * K * N;
    const float* bias_e = biasAll + (size_t)e * N;
    const float*     A_f32 = (const float*)Aall + (size_t)e * M * K;
    const _Float16*  A_f16 = (const _Float16*)Aall + (size_t)e * M * K;

    // --- staging index precompute ---
    // B: thread owns one n-column (bn) and 16 consecutive k's starting at bkh.
    const int bn  = ((tid >> 6) & 1) * 64 + (tid & 63);  // 0..127
    const int bkh = (tid >> 7) * 16;                     // 0 or 16
    // A fp32: thread owns rows {ar, ar+16} x 8 k's at ak.
    const int ar = (tid >> 6) * 32 + ((tid & 63) >> 2);  // 0..15 per half
    const int ak = (tid & 3) * 8;                        // 0,8,16,24
    // A f16: thread owns rows {r, r+64} x 8 k's at c8.
    const int r  = tid >> 2;                             // 0..63
    const int c8 = (tid & 3) * 8;                        // 0,8,16,24

    // --- register staging buffers (the in-flight tile) ---
    float bv[16];
    f32x4 a32[4];   // fp32 A path: rows {ar, ar+16} x 2 f32x4 each
    f16x8 a16[2];   // f16  A path: rows {r, r+64}

    auto load_tile = [&](int k0) {
        const float* bsrc = B_e + (size_t)(k0 + bkh) * N + n0 + bn;
#pragma unroll
        for (int kk = 0; kk < 16; ++kk)
            bv[kk] = bsrc[(size_t)kk * N];   // coalesced: lanes = consecutive n
        if (A_IS_F16) {
            a16[0] = *(const f16x8*)(A_f16 + (size_t)(m0 + r) * K + k0 + c8);
            a16[1] = *(const f16x8*)(A_f16 + (size_t)(m0 + r + 64) * K + k0 + c8);
        } else {
            const float* a0 = A_f32 + (size_t)(m0 + ar) * K + k0 + ak;
            a32[0] = *(const f32x4*)a0;
            a32[1] = *(const f32x4*)(a0 + 4);
            const float* a1 = A_f32 + (size_t)(m0 + ar + 16) * K + k0 + ak;
            a32[2] = *(const f32x4*)a1;
            a32[3] = *(const f32x4*)(a1 + 4);
        }
    };

    auto store_tile = [&](_Float16* dA, _Float16* dB) {
        // B: pack 16 k's for column bn, two conflict-free b128 writes.
        f16x8 w0, w1;
#pragma unroll
        for (int j = 0; j < 4; ++j) {
            ((h2*)&w0)[j] = __builtin_amdgcn_cvt_pkrtz(bv[2 * j],     bv[2 * j + 1]);
            ((h2*)&w1)[j] = __builtin_amdgcn_cvt_pkrtz(bv[8 + 2 * j], bv[8 + 2 * j + 1]);
        }
        *(f16x8*)&dB[bn * LDK + bkh]     = w0;
        *(f16x8*)&dB[bn * LDK + bkh + 8] = w1;
        // A
        if (A_IS_F16) {
            *(f16x8*)&dA[r * LDK + c8]        = a16[0];
            *(f16x8*)&dA[(r + 64) * LDK + c8] = a16[1];
        } else {
#pragma unroll
            for (int p = 0; p < 2; ++p) {
                f16x8 w;
                ((h2*)&w)[0] = __builtin_amdgcn_cvt_pkrtz(a32[2 * p].x, a32[2 * p].y);
                ((h2*)&w)[1] = __builtin_amdgcn_cvt_pkrtz(a32[2 * p].z, a32[2 * p].w);
                ((h2*)&w)[2] = __builtin_amdgcn_cvt_pkrtz(a32[2 * p + 1].x, a32[2 * p + 1].y);
                ((h2*)&w)[3] = __builtin_amdgcn_cvt_pkrtz(a32[2 * p + 1].z, a32[2 * p + 1].w);
                *(f16x8*)&dA[(ar + p * 16) * LDK + ak] = w;
            }
        }
    };

    f32x4 acc[4][4];
    const f32x4 zero = {0.f, 0.f, 0.f, 0.f};
#pragma unroll
    for (int i = 0; i < 4; ++i)
#pragma unroll
        for (int j = 0; j < 4; ++j) acc[i][j] = zero;

    const int nt = K / 32;

    // ---- prologue: tile 0 -> buf0; tile 1 loads in flight ----
    load_tile(0);
    store_tile(sA[0], sB[0]);
    load_tile(32);
    lds_barrier();

    for (int t = 0; t < nt; ++t) {
        const int cur = t & 1;
        const _Float16* rA = sA[cur];
        const _Float16* rB = sB[cur];

        // ---- fragment reads from current buffer ----
        f16x8 af[4], bf[4];
#pragma unroll
        for (int mi = 0; mi < 4; ++mi)
            af[mi] = *(const f16x8*)&rA[(wm + mi * 16 + lrow) * LDK + lk8];
#pragma unroll
        for (int ni = 0; ni < 4; ++ni)
            bf[ni] = *(const f16x8*)&rB[(wn + ni * 16 + lrow) * LDK + lk8];

        // ---- first half of MFMAs ----
#pragma unroll
        for (int mi = 0; mi < 2; ++mi)
#pragma unroll
            for (int ni = 0; ni < 4; ++ni)
                acc[mi][ni] = __builtin_amdgcn_mfma_f32_16x16x32_f16(af[mi], bf[ni], acc[mi][ni], 0, 0, 0);

        // ---- stage tile t+1 into the other buffer (overlaps MFMA pipe) ----
        if (t + 1 < nt) {
            store_tile(sA[cur ^ 1], sB[cur ^ 1]);   // counted vmcnt wait on tile t+1 regs
            if (t + 2 < nt)
                load_tile((t + 2) * 32);            // in flight ACROSS the barrier now
        }

        // ---- second half of MFMAs ----
#pragma unroll
        for (int mi = 2; mi < 4; ++mi)
#pragma unroll
            for (int ni = 0; ni < 4; ++ni)
                acc[mi][ni] = __builtin_amdgcn_mfma_f32_16x16x32_f16(af[mi], bf[ni], acc[mi][ni], 0, 0, 0);

        // one RAW barrier per K-step: drains LDS ops only, NOT the global
        // prefetch (no vmcnt). This is the whole point of R5.
        lds_barrier();
    }

    // ---- epilogue: C/D layout col=lane&15, row=(lane>>4)*4+reg (verified m89/m91) ----
    const int row_base = (lane >> 4) * 4;
#pragma unroll
    for (int ni = 0; ni < 4; ++ni) {
        const int n = n0 + wn + ni * 16 + lrow;
        const float bv2 = bias_e[n];
#pragma unroll
        for (int mi = 0; mi < 4; ++mi) {
            const int mbase = m0 + wm + mi * 16 + row_base;
#pragma unroll
            for (int rr = 0; rr < 4; ++rr) {
                const float val = acc[mi][ni][rr] + bv2;
                const size_t idx = (size_t)e * M * N + (size_t)(mbase + rr) * N + n;
                if (OUT_IS_F16)
                    ((_Float16*)Call)[idx] = (_Float16)val;
                else
                    ((float*)Call)[idx] = val;
            }
        }
    }
}

extern "C" void kernel_launch(void* const* d_in, const int* in_sizes, int n_in,
                              void* d_out, int out_size, void* d_ws, size_t ws_size,
                              hipStream_t stream) {
    (void)in_sizes; (void)n_in; (void)out_size; (void)ws_size;
    const float* x  = (const float*)d_in[0];  // (E,T,H)
    const float* W1 = (const float*)d_in[1];  // (E,H,I)
    const float* b1 = (const float*)d_in[2];  // (E,I)
    const float* W2 = (const float*)d_in[3];  // (E,I,H)
    const float* b2 = (const float*)d_in[4];  // (E,H)
    float* out = (float*)d_out;               // (E*T, H) fp32
    _Float16* hbuf = (_Float16*)d_ws;         // (E,T,I) f16 intermediate, 67.1 MB

    dim3 blk(256, 1, 1);
    dim3 g1(I_ / 128, T_ / 128, E_);  // 32 x 4 x 16 = 2048 blocks
    moe_gemm<false, true><<<g1, blk, 0, stream>>>((const void*)x, W1, b1, (void*)hbuf, T_, I_, H_);
    dim3 g2(H_ / 128, T_ / 128, E_);  // 8 x 4 x 16 = 512 blocks
    moe_gemm<true, false><<<g2, blk, 0, stream>>>((const void*)hbuf, W2, b2, (void*)out, T_, H_, I_);
}